// Round 1
// baseline (636.360 us; speedup 1.0000x reference)
//
#include <hip/hip_runtime.h>
#include <hip/hip_bf16.h>

typedef unsigned short u16;
typedef __attribute__((ext_vector_type(8))) short short8;
typedef __attribute__((ext_vector_type(4))) float float4v;

#define MFMA_BF16(a, b, c) __builtin_amdgcn_mfma_f32_16x16x32_bf16((a), (b), (c), 0, 0, 0)

typedef const __attribute__((address_space(1))) void* gas_ptr;
typedef __attribute__((address_space(3))) void* las_ptr;

__device__ __forceinline__ u16 f2bf(float f) {
  __hip_bfloat16 h = __float2bfloat16(f);
  return __builtin_bit_cast(u16, h);
}

__device__ __forceinline__ void load_lds16(const u16* g, u16* l) {
  __builtin_amdgcn_global_load_lds((gas_ptr)g, (las_ptr)l, 16, 0, 0);
}

// ---------------------------------------------------------------------------
// gemm_bt mainloop: C[128x128] += A[M][K] * Bt[N][K]^T   (m97-style)
// block = 256 threads = 4 waves in 2x2; wave computes 64x64 via 4x4 MFMA tiles
// ---------------------------------------------------------------------------
__device__ __forceinline__ void gemm_mainloop(
    const u16* __restrict__ A, const u16* __restrict__ Bt, int K,
    int m0, int n0, u16* As, u16* Bs, float4v acc[4][4])
{
  const int tid = threadIdx.x;
  const int w = tid >> 6, lane = tid & 63;
  const int wr = w >> 1, wc = w & 1;
  const int lr = lane & 15, lk = (lane >> 4) * 8;
  for (int k0 = 0; k0 < K; k0 += 32) {
#pragma unroll
    for (int c = 0; c < 2; ++c) {
      int idx = c * 256 + w * 64 + lane;        // slot: row = idx>>2, col8 = idx&3
      int r = idx >> 2, c8 = idx & 3;
      load_lds16(A + (size_t)(m0 + r) * K + k0 + c8 * 8, As + (size_t)(c * 256 + w * 64) * 8);
      load_lds16(Bt + (size_t)(n0 + r) * K + k0 + c8 * 8, Bs + (size_t)(c * 256 + w * 64) * 8);
    }
    __syncthreads();   // compiler drains vmcnt before s_barrier
    short8 af[4], bf[4];
#pragma unroll
    for (int mt = 0; mt < 4; ++mt)
      af[mt] = *(const short8*)&As[(wr * 64 + mt * 16 + lr) * 32 + lk];
#pragma unroll
    for (int nt = 0; nt < 4; ++nt)
      bf[nt] = *(const short8*)&Bs[(wc * 64 + nt * 16 + lr) * 32 + lk];
#pragma unroll
    for (int mt = 0; mt < 4; ++mt)
#pragma unroll
      for (int nt = 0; nt < 4; ++nt)
        acc[mt][nt] = MFMA_BF16(af[mt], bf[nt], acc[mt][nt]);
    __syncthreads();
  }
}

// ---------------------------------------------------------------------------
// GEMM 1: QKV projection.  A = tokens_bf [8192][512], Bt = WqkvT [1536][512].
// Epilogue: q,k stored [i][n] bf16; v stored TRANSPOSED vt[b][d][t] bf16.
// ---------------------------------------------------------------------------
__global__ __launch_bounds__(256) void gemm_qkv(
    const u16* __restrict__ A, const u16* __restrict__ Bt,
    const float* __restrict__ bq, const float* __restrict__ bk, const float* __restrict__ bv,
    u16* __restrict__ qo, u16* __restrict__ ko, u16* __restrict__ vto)
{
  __shared__ u16 As[128 * 32], Bs[128 * 32];
  float4v acc[4][4];
#pragma unroll
  for (int mt = 0; mt < 4; ++mt)
#pragma unroll
    for (int nt = 0; nt < 4; ++nt) acc[mt][nt] = (float4v){0.f, 0.f, 0.f, 0.f};
  const int m0 = blockIdx.y * 128, n0 = blockIdx.x * 128;
  gemm_mainloop(A, Bt, 512, m0, n0, As, Bs, acc);
  const int tid = threadIdx.x, w = tid >> 6, lane = tid & 63;
  const int wr = w >> 1, wc = w & 1, lr = lane & 15, lg = lane >> 4;
#pragma unroll
  for (int mt = 0; mt < 4; ++mt) {
#pragma unroll
    for (int nt = 0; nt < 4; ++nt) {
      int n = n0 + wc * 64 + nt * 16 + lr;
#pragma unroll
      for (int r = 0; r < 4; ++r) {
        int i = m0 + wr * 64 + mt * 16 + lg * 4 + r;
        float v = acc[mt][nt][r];
        if (n < 512) {
          qo[(size_t)i * 512 + n] = f2bf(v + bq[n]);
        } else if (n < 1024) {
          ko[(size_t)i * 512 + (n - 512)] = f2bf(v + bk[n - 512]);
        } else {
          int bb = i >> 12, t = i & 4095;
          vto[((size_t)(bb * 512 + (n - 1024))) * 4096 + t] = f2bf(v + bv[n - 1024]);
        }
      }
    }
  }
}

// ---------------------------------------------------------------------------
// GEMM 2: FFN1.  A = x_bf [8192][512], Bt = W1T [2048][512]. relu(x@W1+b1)->bf16
// ---------------------------------------------------------------------------
__global__ __launch_bounds__(256) void gemm_ffn1(
    const u16* __restrict__ A, const u16* __restrict__ Bt,
    const float* __restrict__ b1, u16* __restrict__ h)
{
  __shared__ u16 As[128 * 32], Bs[128 * 32];
  float4v acc[4][4];
#pragma unroll
  for (int mt = 0; mt < 4; ++mt)
#pragma unroll
    for (int nt = 0; nt < 4; ++nt) acc[mt][nt] = (float4v){0.f, 0.f, 0.f, 0.f};
  const int m0 = blockIdx.y * 128, n0 = blockIdx.x * 128;
  gemm_mainloop(A, Bt, 512, m0, n0, As, Bs, acc);
  const int tid = threadIdx.x, w = tid >> 6, lane = tid & 63;
  const int wr = w >> 1, wc = w & 1, lr = lane & 15, lg = lane >> 4;
#pragma unroll
  for (int mt = 0; mt < 4; ++mt) {
#pragma unroll
    for (int nt = 0; nt < 4; ++nt) {
      int n = n0 + wc * 64 + nt * 16 + lr;
#pragma unroll
      for (int r = 0; r < 4; ++r) {
        int i = m0 + wr * 64 + mt * 16 + lg * 4 + r;
        h[(size_t)i * 2048 + n] = f2bf(fmaxf(acc[mt][nt][r] + b1[n], 0.f));
      }
    }
  }
}

// ---------------------------------------------------------------------------
// GEMM 3: FFN2.  A = h [8192][2048], Bt = W2T [512][2048]. y = h@W2+b2 (fp32)
// ---------------------------------------------------------------------------
__global__ __launch_bounds__(256) void gemm_ffn2(
    const u16* __restrict__ A, const u16* __restrict__ Bt,
    const float* __restrict__ b2, float* __restrict__ y)
{
  __shared__ u16 As[128 * 32], Bs[128 * 32];
  float4v acc[4][4];
#pragma unroll
  for (int mt = 0; mt < 4; ++mt)
#pragma unroll
    for (int nt = 0; nt < 4; ++nt) acc[mt][nt] = (float4v){0.f, 0.f, 0.f, 0.f};
  const int m0 = blockIdx.y * 128, n0 = blockIdx.x * 128;
  gemm_mainloop(A, Bt, 2048, m0, n0, As, Bs, acc);
  const int tid = threadIdx.x, w = tid >> 6, lane = tid & 63;
  const int wr = w >> 1, wc = w & 1, lr = lane & 15, lg = lane >> 4;
#pragma unroll
  for (int mt = 0; mt < 4; ++mt) {
#pragma unroll
    for (int nt = 0; nt < 4; ++nt) {
      int n = n0 + wc * 64 + nt * 16 + lr;
#pragma unroll
      for (int r = 0; r < 4; ++r) {
        int i = m0 + wr * 64 + mt * 16 + lg * 4 + r;
        y[(size_t)i * 512 + n] = acc[mt][nt][r] + b2[n];
      }
    }
  }
}

// ---------------------------------------------------------------------------
// Flash attention, causal, distance bias. BM=16 Q-rows/block, BN=64 K-tile.
// 512 blocks, heaviest qt first. Q in registers; K/V B-frags direct from L2.
// S per wave = one 16x16 tile (wave w covers cols w*16..w*16+15 of the K-tile).
// O[16][512]: wave w owns d-cols [w*128, w*128+128) -> 8 accumulators.
// ---------------------------------------------------------------------------
__global__ __launch_bounds__(256) void attn_kernel(
    const u16* __restrict__ q, const u16* __restrict__ k,
    const u16* __restrict__ vt, const float* __restrict__ dsp,
    float* __restrict__ o)
{
  __shared__ float redm[4][16];
  __shared__ float reds[4][16];
  __shared__ u16 Pbuf[16 * 72];   // P tile, row stride 72 (16B-aligned, conflict-reduced)
  const int tid = threadIdx.x, w = tid >> 6, lane = tid & 63;
  const int b = blockIdx.x & 1;
  const int qt = 255 - (blockIdx.x >> 1);   // heavy (large qt) blocks dispatch first
  const int i0 = qt * 16;
  const float ds = dsp[0];
  const float invs = 0.04419417382415922f;  // 1/sqrt(512)
  const float L2E = 1.4426950408889634f;
  const int lr = lane & 15, lg = lane >> 4;

  // Q fragments for rows i0..i0+15 (all 512 k) held in registers (64 VGPR)
  short8 qf[16];
  {
    const u16* qrow = q + ((size_t)(b * 4096 + i0 + lr)) * 512 + lg * 8;
#pragma unroll
    for (int kc = 0; kc < 16; ++kc) qf[kc] = *(const short8*)(qrow + kc * 32);
  }
  float4v oa[8];
#pragma unroll
  for (int nt = 0; nt < 8; ++nt) oa[nt] = (float4v){0.f, 0.f, 0.f, 0.f};
  float m_i[4] = {-__builtin_inff(), -__builtin_inff(), -__builtin_inff(), -__builtin_inff()};
  float l_i[4] = {0.f, 0.f, 0.f, 0.f};

  const int numjt = (i0 + 15) / 64 + 1;
  for (int jt = 0; jt < numjt; ++jt) {
    const int j0 = jt * 64;
    // ---- S = Q @ K^T : wave w computes S[0:16][w*16 : w*16+16] ----
    float4v s = (float4v){0.f, 0.f, 0.f, 0.f};
    const u16* krow = k + ((size_t)(b * 4096 + j0 + w * 16 + lr)) * 512 + lg * 8;
#pragma unroll
    for (int kc = 0; kc < 16; ++kc) {
      short8 bfv = *(const short8*)(krow + kc * 32);
      s = MFMA_BF16(qf[kc], bfv, s);
    }
    // bias + scale + causal mask; per lane: 4 rows (reg), one col
    const int jg = j0 + w * 16 + lr;
    float sv[4], pm[4];
#pragma unroll
    for (int r = 0; r < 4; ++r) {
      int ig = i0 + lg * 4 + r;
      float x = (s[r] - ds * fabsf((float)(ig - jg))) * invs;
      sv[r] = (jg > ig) ? -__builtin_inff() : x;
      pm[r] = sv[r];
    }
    // partial row-max across the 16 lanes sharing (lane>>4)
#pragma unroll
    for (int off = 1; off < 16; off <<= 1)
#pragma unroll
      for (int r = 0; r < 4; ++r) pm[r] = fmaxf(pm[r], __shfl_xor(pm[r], off, 64));
    if (lr == 0) {
#pragma unroll
      for (int r = 0; r < 4; ++r) redm[w][lg * 4 + r] = pm[r];
    }
    __syncthreads();
    // online softmax update (all waves compute identical stats from LDS)
    float alpha[4], p[4];
#pragma unroll
    for (int r = 0; r < 4; ++r) {
      float rm = fmaxf(fmaxf(redm[0][lg * 4 + r], redm[1][lg * 4 + r]),
                       fmaxf(redm[2][lg * 4 + r], redm[3][lg * 4 + r]));
      float mn = fmaxf(m_i[r], rm);
      alpha[r] = exp2f((m_i[r] - mn) * L2E);
      p[r] = exp2f((sv[r] - mn) * L2E);
      m_i[r] = mn;
    }
    float ps[4];
#pragma unroll
    for (int r = 0; r < 4; ++r) {
      Pbuf[(lg * 4 + r) * 72 + w * 16 + lr] = f2bf(p[r]);
      ps[r] = p[r];
    }
#pragma unroll
    for (int off = 1; off < 16; off <<= 1)
#pragma unroll
      for (int r = 0; r < 4; ++r) ps[r] += __shfl_xor(ps[r], off, 64);
    if (lr == 0) {
#pragma unroll
      for (int r = 0; r < 4; ++r) reds[w][lg * 4 + r] = ps[r];
    }
    __syncthreads();
#pragma unroll
    for (int r = 0; r < 4; ++r)
      l_i[r] = alpha[r] * l_i[r] +
               (reds[0][lg * 4 + r] + reds[1][lg * 4 + r] + reds[2][lg * 4 + r] + reds[3][lg * 4 + r]);
    // rescale O by alpha (row = lg*4 + r for every accumulator)
#pragma unroll
    for (int nt = 0; nt < 8; ++nt)
#pragma unroll
      for (int r = 0; r < 4; ++r) oa[nt][r] *= alpha[r];
    // ---- O += P @ V : A = Pbuf (LDS), B = Vt rows d = w*128 + nt*16 + lr ----
    const u16* vbase = vt + ((size_t)(b * 512 + w * 128)) * 4096 + j0 + lg * 8;
#pragma unroll
    for (int kc2 = 0; kc2 < 2; ++kc2) {
      short8 pf = *(const short8*)&Pbuf[lr * 72 + kc2 * 32 + lg * 8];
#pragma unroll
      for (int nt = 0; nt < 8; ++nt) {
        short8 vf = *(const short8*)(vbase + (size_t)(nt * 16 + lr) * 4096 + kc2 * 32);
        oa[nt] = MFMA_BF16(pf, vf, oa[nt]);
      }
    }
    __syncthreads();   // protect Pbuf/redm/reds for next iteration
  }
  // epilogue: out = O / l
  float* ob = o + ((size_t)(b * 4096 + i0)) * 512 + w * 128;
#pragma unroll
  for (int nt = 0; nt < 8; ++nt) {
#pragma unroll
    for (int r = 0; r < 4; ++r) {
      ob[(size_t)(lg * 4 + r) * 512 + nt * 16 + lr] = oa[nt][r] / l_i[r];
    }
  }
}

// ---------------------------------------------------------------------------
// LayerNorm over 512: one wave per row. out = (a+bsrc - mu)*rs*g + be
// writes fp32 always, bf16 copy if ob != nullptr.
// ---------------------------------------------------------------------------
__global__ __launch_bounds__(256) void ln_kernel(
    const float* __restrict__ a, const float* __restrict__ bsrc,
    const float* __restrict__ g, const float* __restrict__ be,
    float* __restrict__ of, u16* __restrict__ ob)
{
  const int row = blockIdx.x * 4 + (threadIdx.x >> 6);
  const int lane = threadIdx.x & 63;
  const size_t base = (size_t)row * 512 + lane * 8;
  float v[8];
#pragma unroll
  for (int t = 0; t < 8; ++t) v[t] = a[base + t] + bsrc[base + t];
  float s = 0.f;
#pragma unroll
  for (int t = 0; t < 8; ++t) s += v[t];
#pragma unroll
  for (int off = 1; off < 64; off <<= 1) s += __shfl_xor(s, off, 64);
  const float mu = s * (1.0f / 512.0f);
  float qv = 0.f;
#pragma unroll
  for (int t = 0; t < 8; ++t) { float d = v[t] - mu; qv += d * d; }
#pragma unroll
  for (int off = 1; off < 64; off <<= 1) qv += __shfl_xor(qv, off, 64);
  const float rs = rsqrtf(qv * (1.0f / 512.0f) + 1e-5f);
  const int cb = lane * 8;
#pragma unroll
  for (int t = 0; t < 8; ++t) {
    float xv = (v[t] - mu) * rs * g[cb + t] + be[cb + t];
    of[base + t] = xv;
    if (ob) ob[base + t] = f2bf(xv);
  }
}

// ---------------------------------------------------------------------------
// prep kernels
// ---------------------------------------------------------------------------
__global__ __launch_bounds__(256) void cast_bf_kernel(
    const float* __restrict__ in, u16* __restrict__ out)
{
  const size_t i = ((size_t)blockIdx.x * 256 + threadIdx.x) * 8;
#pragma unroll
  for (int t = 0; t < 8; ++t) out[i + t] = f2bf(in[i + t]);
}

__global__ __launch_bounds__(256) void transpose_bf_kernel(
    const float* __restrict__ src, u16* __restrict__ dst, int K, int N)
{
  int t = blockIdx.x * 256 + threadIdx.x;
  if (t >= K * N) return;
  int kk = t / N, n = t - kk * N;
  dst[(size_t)n * K + kk] = f2bf(src[t]);
}

// ---------------------------------------------------------------------------
// launch
// ---------------------------------------------------------------------------
extern "C" void kernel_launch(void* const* d_in, const int* in_sizes, int n_in,
                              void* d_out, int out_size, void* d_ws, size_t ws_size,
                              hipStream_t stream) {
  const float* tokens = (const float*)d_in[0];
  const float* Wq = (const float*)d_in[1];
  const float* bq = (const float*)d_in[2];
  const float* Wk = (const float*)d_in[3];
  const float* bk = (const float*)d_in[4];
  const float* Wv = (const float*)d_in[5];
  const float* bv = (const float*)d_in[6];
  const float* dscale = (const float*)d_in[7];
  const float* W1 = (const float*)d_in[8];
  const float* b1 = (const float*)d_in[9];
  const float* W2 = (const float*)d_in[10];
  const float* b2 = (const float*)d_in[11];
  const float* g1 = (const float*)d_in[12];
  const float* be1 = (const float*)d_in[13];
  const float* g2 = (const float*)d_in[14];
  const float* be2 = (const float*)d_in[15];
  float* out = (float*)d_out;

  // workspace layout (bytes). hbuf reuses q/k/vt/attn region (dead after LN1).
  char* ws = (char*)d_ws;
  u16*   tok_bf = (u16*)(ws + 0);            //  8192*512  bf16   [0,        8388608)
  u16*   wqkvT  = (u16*)(ws + 8388608);      //  1536*512  bf16   [8388608,  9961472)
  u16*   w1T    = (u16*)(ws + 9961472);      //  2048*512  bf16   [9961472, 12058624)
  u16*   w2T    = (u16*)(ws + 12058624);     //  512*2048  bf16   [12058624,14155776)
  u16*   qbuf   = (u16*)(ws + 14155776);     //  2*4096*512 bf16
  u16*   kbuf   = (u16*)(ws + 22544384);
  u16*   vtbuf  = (u16*)(ws + 30932992);     //  vt[b][d][t]
  float* attnb  = (float*)(ws + 39321600);   //  8192*512 f32    [..,56098816)
  float* xf     = (float*)(ws + 56098816);   //  8192*512 f32    [..,72876032)
  u16*   xbf    = (u16*)(ws + 72876032);     //  8192*512 bf16   [..,81264640)
  u16*   hbuf   = (u16*)(ws + 14155776);     //  8192*2048 bf16 (reuse, ends 47710208)
  float* ybuf   = (float*)(ws + 81264640);   //  8192*512 f32    [..,98041856)

  // prep: bf16 casts + weight transposes (Wt[n][k] = W[k][n])
  cast_bf_kernel<<<2048, 256, 0, stream>>>(tokens, tok_bf);
  transpose_bf_kernel<<<1024, 256, 0, stream>>>(Wq, wqkvT, 512, 512);
  transpose_bf_kernel<<<1024, 256, 0, stream>>>(Wk, wqkvT + 512 * 512, 512, 512);
  transpose_bf_kernel<<<1024, 256, 0, stream>>>(Wv, wqkvT + 1024 * 512, 512, 512);
  transpose_bf_kernel<<<4096, 256, 0, stream>>>(W1, w1T, 512, 2048);
  transpose_bf_kernel<<<4096, 256, 0, stream>>>(W2, w2T, 2048, 512);

  // QKV projection (M=8192, N=1536, K=512)
  gemm_qkv<<<dim3(12, 64), 256, 0, stream>>>(tok_bf, wqkvT, bq, bk, bv, qbuf, kbuf, vtbuf);

  // flash attention (512 blocks, heavy-first)
  attn_kernel<<<512, 256, 0, stream>>>(qbuf, kbuf, vtbuf, dscale, attnb);

  // LN1: x = LN(tokens + attn)
  ln_kernel<<<2048, 256, 0, stream>>>(attnb, tokens, g1, be1, xf, xbf);

  // FFN1: h = relu(x@W1 + b1)   (M=8192, N=2048, K=512)
  gemm_ffn1<<<dim3(16, 64), 256, 0, stream>>>(xbf, w1T, b1, hbuf);

  // FFN2: y = h@W2 + b2         (M=8192, N=512, K=2048)
  gemm_ffn2<<<dim3(4, 64), 256, 0, stream>>>(hbuf, w2T, b2, ybuf);

  // LN2: out = LN(y + x)
  ln_kernel<<<2048, 256, 0, stream>>>(ybuf, xf, g2, be2, out, nullptr);
}